// Round 12
// baseline (191.904 us; speedup 1.0000x reference)
//
#include <hip/hip_runtime.h>
#include <hip/hip_fp16.h>
#include <math.h>

#define HH 512
#define WW 512
#define BB 4
#define NPIX (BB * HH * WW)

#define HS 4                  // core rows per wave
#define NSX 9                 // strips of 60 core cols
#define NBAND (HH / HS)       // 128
#define NWAVES (NSX * NBAND * BB)   // 4608
#define NBLK (NWAVES / 4)           // 1152

constexpr float TAUf   = 0.01f;
constexpr float RHOf   = 1.99f;
constexpr float SIGMAf = (float)(1.0 / 0.01 / 72.0);
constexpr float INV1PT = (float)(1.0 / 1.01);

__device__ __forceinline__ float cf(__half h) { return __half2float(h); }
__device__ __forceinline__ float SD(float v)  { return __shfl_down(v, 1, 64); }
__device__ __forceinline__ float SUp(float v) { return __shfl_up(v, 1, 64); }
__device__ __forceinline__ unsigned SDu(unsigned v) {
    return (unsigned)__shfl_down((int)v, 1, 64);
}
__device__ __forceinline__ float2 h2f(unsigned v) {
    __half2 h = *reinterpret_cast<__half2*>(&v);
    return make_float2(__low2float(h), __high2float(h));
}

// R10 skeleton with ALL global loads hoisted to the prologue.
// Step k stages: u''-store row R0+k-8 | i row R0+k-3 | s,t row R0+k-4 | v row R0+k-6
// MODE: 0 = iter0 (x=y, r=0, u=0); 1 = mid; 2 = last (x-only, f32 out)
template <int MODE>
__global__ __launch_bounds__(256, 4) void sweep(
    const float* __restrict__ y, const int* __restrict__ ths_p,
    const __half* __restrict__ x2_in, const __half* __restrict__ r2_in,
    const __half* __restrict__ u_in,
    __half* __restrict__ x2_out, __half* __restrict__ r2_out,
    __half* __restrict__ u_out, float* __restrict__ xout)
{
    const int tid  = threadIdx.x;
    const int lane = tid & 63;
    const int wid  = blockIdx.x * 4 + (tid >> 6);
    const int sx   = wid % NSX;
    const int t2   = wid / NSX;
    const int band = t2 & (NBAND - 1);
    const int b    = t2 / NBAND;
    const int R0   = band * HS;
    const int w    = sx * 60 - 2 + lane;
    const int boff = b * (HH * WW);
    const bool wok = ((unsigned)w) < (unsigned)WW;
    const float mA = (w >= 1 && w < WW) ? 1.f : 0.f;
    const float mB = (w >= 0 && w < WW - 1) ? 1.f : 0.f;
    const bool cok = (lane >= 2) && (lane < 62) && (w < WW);

    const float ths     = (float)ths_p[0];
    const float inv_tl1 = 1.0f / (TAUf * (ths * 0.1f));
    const float inv_l2  = 1.0f / (ths * 0.15f);

    // ---------- FULL PREFETCH ----------
    // u rows R0-3 .. R0+6  (index j = row - (R0-3))
    uint2 araw[10];
    #pragma unroll
    for (int j = 0; j < 10; ++j) { araw[j].x = 0u; araw[j].y = 0u; }
    if (MODE != 0) {
        #pragma unroll
        for (int j = 0; j < 10; ++j) {
            int row = R0 - 3 + j;
            if (((unsigned)row) < (unsigned)HH && wok)
                araw[j] = *(const uint2*)(u_in + 4 * (size_t)(boff + row * WW + w));
        }
    }
    // scalar rows R0-1 .. R0+5 (index j = row - (R0-1))
    float sy[7]; float sx2[7]; unsigned sr2[7];
    #pragma unroll
    for (int j = 0; j < 7; ++j) { sy[j] = 0.f; sx2[j] = 0.f; sr2[j] = 0u; }
    #pragma unroll
    for (int j = 0; j < 7; ++j) {
        int row = R0 - 1 + j;
        bool ok = (((unsigned)row) < (unsigned)HH) && wok;
        if (ok) {
            int idx = boff + row * WW + w;
            sy[j] = y[idx];
            if (MODE != 0) sx2[j] = cf(x2_in[idx]);
            if (MODE == 1) sr2[j] = *(const unsigned*)(r2_in + 2 * (size_t)idx);
        }
    }

    // rings (produced in-loop; slots fold under full unroll)
    float i0r[4], i1r[4];
    float srg[4], t0rg[4], t1rg[4];
    float v0rg[4], v1rg[4];
    #pragma unroll
    for (int q = 0; q < 4; ++q) {
        i0r[q]=i1r[q]=srg[q]=t0rg[q]=t1rg[q]=v0rg[q]=v1rg[q]=0.f;
    }

    constexpr int NSTEP  = (MODE == 2) ? (HS + 4) : (HS + 8);
    constexpr int KI_LO  = (MODE == 2) ? 2 : 1;
    constexpr int KI_HI  = (MODE == 2) ? (HS + 2) : (HS + 4);
    constexpr int KS_LO  = (MODE == 2) ? 4 : 3;
    constexpr int KS_HI  = (MODE == 2) ? (HS + 3) : (HS + 5);

    #pragma unroll
    for (int k = 0; k < NSTEP; ++k) {

        // ---- u''-stage: row ro = R0+k-8 ----
        if (MODE != 2 && k >= 8) {
            const int ro = R0 + k - 8;   // core row, always in-image
            float a0, a1, a2, a3;
            if (MODE == 0) { a0 = a1 = a2 = a3 = 0.f; }
            else {
                uint2 rr_ = araw[k - 5];              // row ro
                float2 p = h2f(rr_.x), q = h2f(rr_.y);
                a0 = p.x; a1 = p.y; a2 = q.x; a3 = q.y;
            }
            float v0c = v0rg[(k - 2) & 3], v0u = v0rg[(k - 3) & 3];
            float v1c = v1rg[(k - 2) & 3], v1d = v1rg[(k - 1) & 3];
            float hD = (ro < HH - 1) ? 1.f : 0.f;
            float G0 = v0c - v0u;
            float G1 = mA * (v0c - SUp(v0c));
            float G2 = v1c - mA * SUp(v1c);
            float G3 = hD * (v1d - v1c);
            float b0 = a0 + SIGMAf * G0, b1 = a1 + SIGMAf * G1;
            float b2 = a2 + SIGMAf * G2, b3 = a3 + SIGMAf * G3;
            float mag = sqrtf(b0 * b0 + b1 * b1 + b2 * b2 + b3 * b3) * inv_l2;
            float ui = 1.f / fmaxf(mag, 1.f);
            if (cok) {
                int idx = boff + ro * WW + w;
                __half2 lo = __floats2half2_rn(a0 + RHOf * (b0 * ui - a0),
                                               a1 + RHOf * (b1 * ui - a1));
                __half2 hi = __floats2half2_rn(a2 + RHOf * (b2 * ui - a2),
                                               a3 + RHOf * (b3 * ui - a3));
                uint2 st; st.x = *(unsigned*)&lo; st.y = *(unsigned*)&hi;
                *(uint2*)(u_out + 4 * (size_t)idx) = st;
            }
        }

        // ---- i-stage: row ri = R0+k-3 ----
        if (MODE != 0 && k >= KI_LO && k <= KI_HI) {
            const int ri = R0 + k - 3;
            if (((unsigned)ri) < (unsigned)HH) {
                uint2 rc = araw[k];       // row ri
                uint2 rd = araw[k + 1];   // row ri+1
                uint2 ru = araw[k - 1];   // row ri-1
                float2 c01 = h2f(rc.x), c23 = h2f(rc.y);
                float2 d01 = h2f(rd.x);
                float2 u23 = h2f(ru.y);
                float2 s01 = h2f(SDu(rc.x));
                float2 s23 = h2f(SDu(rc.y));
                float hD = (ri < HH - 1) ? 1.f : 0.f;
                i0r[k & 3] = c01.x - d01.x - s01.y + mA * c01.y;
                i1r[k & 3] = c23.x - s23.x - hD * c23.y + u23.y;
            } else { i0r[k & 3] = 0.f; i1r[k & 3] = 0.f; }
        }

        // ---- s,t-stage: row rs = R0+k-4 ----
        if (k >= KS_LO && k <= KS_HI) {
            const int rs = R0 + k - 4;
            const bool coreRow = (k >= 4) && (k <= HS + 3);
            float sv = 0.f, t0v = 0.f, t1v = 0.f;
            if (((unsigned)rs) < (unsigned)HH) {
                float yv = sy[k - 3];
                if (MODE == 0) {
                    sv = yv;
                    if (coreRow && cok) {
                        int idx = boff + rs * WW + w;
                        x2_out[idx] = __float2half(yv);
                        *(__half2*)(r2_out + 2 * (size_t)idx) =
                            __floats2half2_rn(0.f, 0.f);
                    }
                } else {
                    float i0c = i0r[(k - 1) & 3], i1c = i1r[(k - 1) & 3];
                    float i1u = i1r[(k - 2) & 3];
                    float i0l = SUp(i0c);
                    float hD = (rs < HH - 1) ? 1.f : 0.f;
                    float na = TAUf * (mA * i0l - mB * i0c + i1u - hD * i1c);
                    float x2v = sx2[k - 3];
                    float x = (x2v - na + TAUf * yv) * INV1PT;
                    if (MODE == 2) {
                        if (coreRow && cok)
                            xout[boff + rs * WW + w] = x2v + RHOf * (x - x2v);
                    } else {
                        float2 rv2 = h2f(sr2[k - 3]);
                        float r20v = rv2.x, r21v = rv2.y;
                        float rr0 = r20v + TAUf * i0c, rr1 = r21v + TAUf * i1c;
                        float mag = sqrtf(rr0 * rr0 + rr1 * rr1) * inv_tl1;
                        float ri_ = 1.f / fmaxf(mag, 1.f);
                        float q0 = rr0 - rr0 * ri_, q1 = rr1 - rr1 * ri_;
                        sv = 2.f * x - x2v;
                        t0v = 2.f * q0 - r20v;
                        t1v = 2.f * q1 - r21v;
                        if (coreRow && cok) {
                            int idx = boff + rs * WW + w;
                            x2_out[idx] = __float2half(x2v + RHOf * (x - x2v));
                            *(__half2*)(r2_out + 2 * (size_t)idx) = __floats2half2_rn(
                                r20v + RHOf * (q0 - r20v), r21v + RHOf * (q1 - r21v));
                        }
                    }
                }
            }
            if (MODE != 2) { srg[k & 3] = sv; t0rg[k & 3] = t0v; t1rg[k & 3] = t1v; }
        }

        // ---- v-stage: row rv = R0+k-6 ----
        if (MODE != 2 && k >= 5 && k <= HS + 6) {
            const int rv = R0 + k - 6;
            float v0 = 0.f, v1 = 0.f;
            if (((unsigned)rv) < (unsigned)HH) {
                float sc = srg[(k - 2) & 3];
                float sn = srg[(k - 1) & 3];
                float t0c = t0rg[(k - 2) & 3], t1c = t1rg[(k - 2) & 3];
                float hD = (rv < HH - 1) ? 1.f : 0.f;
                v0 = mB * (SD(sc) - sc) - t0c;
                v1 = hD * (sn - sc) - t1c;
            }
            v0rg[k & 3] = v0;
            v1rg[k & 3] = v1;
        }
    }
}

extern "C" void kernel_launch(void* const* d_in, const int* in_sizes, int n_in,
                              void* d_out, int out_size, void* d_ws, size_t ws_size,
                              hipStream_t stream)
{
    const float* y   = (const float*)d_in[0];
    const int*   ths = (const int*)d_in[1];
    __half* ws = (__half*)d_ws;

    __half* Ax2 = ws;
    __half* Ar2 = ws + (size_t)NPIX;
    __half* Au  = ws + (size_t)3 * NPIX;
    __half* Bx2 = ws + (size_t)7 * NPIX;
    __half* Br2 = ws + (size_t)8 * NPIX;
    __half* Bu  = ws + (size_t)10 * NPIX;
    float*  xout = (float*)d_out;

    dim3 block(256);
    dim3 grid(NBLK);

    // iter 0 (analytic) -> B
    sweep<0><<<grid, block, 0, stream>>>(y, ths, Ax2, Ar2, Au, Bx2, Br2, Bu, nullptr);
    // iters 1..8 alternate
    __half *ix2 = Bx2, *ir2 = Br2, *iu = Bu;
    __half *ox2 = Ax2, *or2 = Ar2, *ou = Au;
    for (int it = 1; it <= 8; ++it) {
        sweep<1><<<grid, block, 0, stream>>>(y, ths, ix2, ir2, iu, ox2, or2, ou, nullptr);
        __half* t;
        t = ix2; ix2 = ox2; ox2 = t;
        t = ir2; ir2 = or2; or2 = t;
        t = iu;  iu  = ou;  ou  = t;
    }
    // iter 9: x only -> d_out
    sweep<2><<<grid, block, 0, stream>>>(y, ths, ix2, ir2, iu, nullptr, nullptr, nullptr, xout);
}